// Round 7
// baseline (276.337 us; speedup 1.0000x reference)
//
#include <hip/hip_runtime.h>
#include <math.h>

#define NN 10000
#define NE 160000
#define NRBF 50
#define WNUM 2304
#define EPSV 1e-5f

#define A_P1 0.125f
#define A_P2 0.17677669529663687f
#define A_P3 0.125f
#define A_P4 0.17677669529663687f
#define INV_SQRT3 0.5773502691896258f
#define INV_SQRT_M0 0.17677669529663687f
#define INV_SQRT_M1 0.25f

typedef __attribute__((ext_vector_type(8))) short bf16x8;
typedef __attribute__((ext_vector_type(4))) short s16x4;
typedef __attribute__((ext_vector_type(4))) float f32x4;
typedef __attribute__((ext_vector_type(4))) int i32x4;

#define MFMA16(a, b, c) __builtin_amdgcn_mfma_f32_16x16x32_bf16(a, b, c, 0, 0, 0)

__device__ __forceinline__ short f2bf(float x) {
  unsigned u = __float_as_uint(x);
  unsigned r = (u + 0x7fffu + ((u >> 16) & 1u)) >> 16;
  return (short)r;
}
__device__ __forceinline__ float bf2f(short s) {
  return __uint_as_float(((unsigned)(unsigned short)s) << 16);
}

// ---- weight prep: transpose + bf16 + fragment-order packing ----
// Per 16-col tile t: 1024 shorts = [chunk(2)][lane(64)][kk(8)].
__global__ void prep_weights(const float* __restrict__ W1, const float* __restrict__ W2,
                             const float* __restrict__ W3, short* __restrict__ W1P,
                             short* __restrict__ W2P, short* __restrict__ W3P) {
  int s = blockIdx.x * 256 + threadIdx.x;
  if (s < WNUM * 64) {
    int t = s >> 10, r = s & 1023;
    int ch = r >> 9, l = (r >> 3) & 63, kk = r & 7;
    int row = t * 16 + (l & 15);
    int k = ((l >> 4) << 3) + (ch << 5) + kk;
    W3P[s] = f2bf(W3[k * WNUM + row]);
  } else if (s < WNUM * 64 + 4096) {
    int s2 = s - WNUM * 64;
    int t = s2 >> 10, r = s2 & 1023;
    int ch = r >> 9, l = (r >> 3) & 63, kk = r & 7;
    int row = t * 16 + (l & 15);
    int k = ((l >> 4) << 3) + (ch << 5) + kk;
    W1P[s2] = f2bf(k < NRBF ? W1[k * 64 + row] : 0.f);
  } else if (s < WNUM * 64 + 8192) {
    int s2 = s - WNUM * 64 - 4096;
    int t = s2 >> 10, r = s2 & 1023;
    int ch = r >> 9, l = (r >> 3) & 63, kk = r & 7;
    int row = t * 16 + (l & 15);
    int k = ((l >> 4) << 3) + (ch << 5) + kk;
    W2P[s2] = f2bf(W2[k * 64 + row]);
  }
}

// ---- CSR build ----
__global__ void edge_count(const int* __restrict__ eidx, int* __restrict__ deg) {
  int e = blockIdx.x * 256 + threadIdx.x;
  if (e < NE) atomicAdd(&deg[eidx[NE + e]], 1);
}

__global__ __launch_bounds__(256) void scan_deg(const int* __restrict__ deg,
                                                int* __restrict__ offs) {
  __shared__ int chunk[10240];
  __shared__ int part[256];
  const int tid = threadIdx.x;
  const int base = tid * 40;
  int s = 0;
  for (int i = 0; i < 40; i++) {
    int idx = base + i;
    int v = (idx < NN) ? deg[idx] : 0;
    chunk[base + i] = s;
    s += v;
  }
  const int tot = s;
  part[tid] = s;
  __syncthreads();
  for (int d = 1; d < 256; d <<= 1) {
    int v = (tid >= d) ? part[tid - d] : 0;
    __syncthreads();
    if (tid >= d) part[tid] += v;
    __syncthreads();
  }
  int excl = part[tid] - tot;
  for (int i = 0; i < 40; i++) {
    int idx = base + i;
    if (idx < NN) offs[idx] = chunk[base + i] + excl;
  }
  if (tid == 255) offs[NN] = part[255];
}

__global__ void edge_place(const int* __restrict__ eidx, const int* __restrict__ offs,
                           int* __restrict__ slot, int* __restrict__ csr) {
  int e = blockIdx.x * 256 + threadIdx.x;
  if (e < NE) {
    int d = eidx[NE + e];
    int pos = offs[d] + atomicAdd(&slot[d], 1);
    csr[pos] = e;
  }
}

// One 16-col tile T for ALL 4 edge-groups: 2 B loads + bias, 8 MFMA, custom fold.
#define TILE4(T, ...)                                               \
  {                                                                 \
    const short* _wb = W3P + ((T) << 10) + (l << 3);                \
    bf16x8 _B0 = *(const bf16x8*)_wb;                               \
    bf16x8 _B1 = *(const bf16x8*)(_wb + 512);                       \
    float _bias = b3[((T) << 4) + lr];                              \
    _Pragma("unroll")                                               \
    for (int g = 0; g < 4; ++g) {                                   \
      f32x4 _d = {_bias, _bias, _bias, _bias};                      \
      _d = MFMA16(a0g[g], _B0, _d);                                 \
      f32x4 v = MFMA16(a1g[g], _B1, _d);                            \
      __VA_ARGS__                                                   \
    }                                                               \
  }

__global__ __launch_bounds__(256, 4) void edge_kernel(
    const float* __restrict__ h, const int* __restrict__ eidx,
    const float* __restrict__ esh, const float* __restrict__ ef,
    const short* __restrict__ W1P, const float* __restrict__ b1,
    const short* __restrict__ W2P, const float* __restrict__ b2,
    const short* __restrict__ W3P, const float* __restrict__ b3,
    float* __restrict__ agg, float* __restrict__ msg, int use_csr) {
  // SM: buf0 [64][72] sh | m0c [48][64] sh | m1c [3][48][64] sh  = 16896 sh
  // After phase C, first 6656 floats reused as reduce scratch / msg bounce.
  __shared__ short SM[16896];
  __shared__ int dsts[64];
  __shared__ float b1s[64], b2s[64];
  short* buf0 = SM;
  short* M0C = SM + 4608;
  short* M1C = SM + 7680;
  float* scratch = (float*)SM;

  const int tid = threadIdx.x;
  const int e0 = blockIdx.x * 64;

  // ---- Phase A: staging ----
  for (int idx = tid; idx < 64 * 64; idx += 256) {
    int e = idx >> 6, k = idx & 63;
    float v = (k < NRBF) ? ef[(long)(e0 + e) * NRBF + k] : 0.f;
    buf0[e * 72 + k] = f2bf(v);
  }
  if (tid < 64) { b1s[tid] = b1[tid]; b2s[tid] = b2[tid]; }
  {
    int e = tid >> 2, q = tid & 3;
    int ge = e0 + e;
    int src = eidx[ge];
    float y0 = esh[ge * 4 + 0];
    float y1x = esh[ge * 4 + 1], y1y = esh[ge * 4 + 2], y1z = esh[ge * 4 + 3];
    const float* hs = h + (long)src * 80;
    for (int u = q; u < 32; u += 4) {
      float s = hs[u];
      M0C[u * 64 + e] = f2bf(A_P1 * y0 * s);            // w1 coef (y0 baked)
      float t = A_P3 * s;                               // w3 coef (y1 baked)
      M1C[(16 + u) * 64 + e] = f2bf(t * y1x);
      M1C[(48 + 16 + u) * 64 + e] = f2bf(t * y1y);
      M1C[(96 + 16 + u) * 64 + e] = f2bf(t * y1z);
    }
    for (int u = q; u < 16; u += 4) {
      float sx = hs[32 + u * 3], sy = hs[33 + u * 3], sz = hs[34 + u * 3];
      M1C[u * 64 + e] = f2bf(A_P2 * y0 * sx);           // w2 coef (y0 baked)
      M1C[(48 + u) * 64 + e] = f2bf(A_P2 * y0 * sy);
      M1C[(96 + u) * 64 + e] = f2bf(A_P2 * y0 * sz);
      M0C[(32 + u) * 64 + e] =                           // w4 coef
          f2bf(A_P4 * INV_SQRT3 * (sx * y1x + sy * y1y + sz * y1z));
    }
    if (q == 0) dsts[e] = eidx[NE + ge];
  }
  __syncthreads();

  const int wid = tid >> 6, l = tid & 63;
  const int lr = l & 15, lg = l >> 4;
  const int g16 = lg * 4;
  const int er = wid * 16;

  // ---- MLP layer 1 (in place in buf0; rows are wave-private) ----
  {
    bf16x8 a0 = *(const bf16x8*)&buf0[(er + lr) * 72 + lg * 8];
    bf16x8 a1 = *(const bf16x8*)&buf0[(er + lr) * 72 + 32 + lg * 8];
#pragma unroll
    for (int jt = 0; jt < 4; ++jt) {
      const short* wb = W1P + (jt << 10) + (l << 3);
      bf16x8 b0 = *(const bf16x8*)wb;
      bf16x8 b1f = *(const bf16x8*)(wb + 512);
      float bias = b1s[jt * 16 + lr];
      f32x4 d = {bias, bias, bias, bias};
      d = MFMA16(a0, b0, d);
      d = MFMA16(a1, b1f, d);
#pragma unroll
      for (int r = 0; r < 4; ++r) {
        float x = d[r];
        x = x / (1.f + __expf(-x));
        buf0[(er + lg * 4 + r) * 72 + jt * 16 + lr] = f2bf(x);
      }
    }
  }
  __syncthreads();

  // ---- MLP layer 2 (in place) ----
  {
    bf16x8 a0 = *(const bf16x8*)&buf0[(er + lr) * 72 + lg * 8];
    bf16x8 a1 = *(const bf16x8*)&buf0[(er + lr) * 72 + 32 + lg * 8];
#pragma unroll
    for (int jt = 0; jt < 4; ++jt) {
      const short* wb = W2P + (jt << 10) + (l << 3);
      bf16x8 b0 = *(const bf16x8*)wb;
      bf16x8 b1f = *(const bf16x8*)(wb + 512);
      float bias = b2s[jt * 16 + lr];
      f32x4 d = {bias, bias, bias, bias};
      d = MFMA16(a0, b0, d);
      d = MFMA16(a1, b1f, d);
#pragma unroll
      for (int r = 0; r < 4; ++r) {
        float x = d[r];
        x = x / (1.f + __expf(-x));
        buf0[(er + lg * 4 + r) * 72 + jt * 16 + lr] = f2bf(x);
      }
    }
  }
  __syncthreads();

  // ---- Phase C: region-split waves; all 4 edge-groups per wave ----
  bf16x8 a0g[4], a1g[4];
#pragma unroll
  for (int g = 0; g < 4; ++g) {
    a0g[g] = *(const bf16x8*)&buf0[(g * 16 + lr) * 72 + lg * 8];
    a1g[g] = *(const bf16x8*)&buf0[(g * 16 + lr) * 72 + 32 + lg * 8];
  }

  // waves 0,1: acc[0]=m0 cols0-15, acc[1]=m0 cols16-31 (acc[2] unused)
  // waves 2,3: acc[0..2] = m1 x,y,z
  f32x4 acc[3][4];
#pragma unroll
  for (int j = 0; j < 3; ++j)
#pragma unroll
    for (int g = 0; g < 4; ++g) acc[j][g] = (f32x4){0, 0, 0, 0};

#define FOLD_M0(U, TEVEN)                                              \
  TILE4(TEVEN, {                                                       \
    s16x4 cc = *(const s16x4*)&M0C[(U)*64 + g * 16 + g16];             \
    _Pragma("unroll") for (int r = 0; r < 4; ++r)                      \
        acc[0][g][r] += bf2f(cc[r]) * v[r];                            \
  });                                                                  \
  TILE4((TEVEN) + 1, {                                                 \
    s16x4 cc = *(const s16x4*)&M0C[(U)*64 + g * 16 + g16];             \
    _Pragma("unroll") for (int r = 0; r < 4; ++r)                      \
        acc[1][g][r] += bf2f(cc[r]) * v[r];                            \
  })

#define FOLD_M1(U)                                                     \
  TILE4(64 + (U), {                                                    \
    s16x4 c0 = *(const s16x4*)&M1C[(U)*64 + g * 16 + g16];             \
    s16x4 c1 = *(const s16x4*)&M1C[(48 + (U)) * 64 + g * 16 + g16];    \
    s16x4 c2 = *(const s16x4*)&M1C[(96 + (U)) * 64 + g * 16 + g16];    \
    _Pragma("unroll") for (int r = 0; r < 4; ++r) {                    \
      acc[0][g][r] += bf2f(c0[r]) * v[r];                              \
      acc[1][g][r] += bf2f(c1[r]) * v[r];                              \
      acc[2][g][r] += bf2f(c2[r]) * v[r];                              \
    }                                                                  \
  })

  if (wid == 0) {
#pragma unroll 2
    for (int u = 0; u < 24; ++u) { FOLD_M0(u, 2 * u); }
  } else if (wid == 1) {
#pragma unroll 2
    for (int u = 24; u < 32; ++u) { FOLD_M0(u, 2 * u); }
#pragma unroll 2
    for (int u = 32; u < 48; ++u) { FOLD_M0(u, 2 * u + 48); }
  } else if (wid == 2) {
#pragma unroll 2
    for (int u = 0; u < 24; ++u) { FOLD_M1(u); }
  } else {
#pragma unroll 2
    for (int u = 24; u < 48; ++u) { FOLD_M1(u); }
  }

  // ---- single-round cross-wave reduce (scratch stride 52, 16B aligned) ----
  __syncthreads();  // coef/buf0 reads done; scratch reuse is safe
  if (wid == 1) {
#pragma unroll
    for (int g = 0; g < 4; ++g) {
      *(f32x4*)&scratch[l * 52 + g * 8] = acc[0][g];
      *(f32x4*)&scratch[l * 52 + g * 8 + 4] = acc[1][g];
    }
  }
  if (wid == 3) {
#pragma unroll
    for (int g = 0; g < 4; ++g) {
      *(f32x4*)&scratch[3328 + l * 52 + g * 12] = acc[0][g];
      *(f32x4*)&scratch[3328 + l * 52 + g * 12 + 4] = acc[1][g];
      *(f32x4*)&scratch[3328 + l * 52 + g * 12 + 8] = acc[2][g];
    }
  }
  __syncthreads();
  if (wid == 0) {
#pragma unroll
    for (int g = 0; g < 4; ++g) {
      f32x4 t0 = *(const f32x4*)&scratch[l * 52 + g * 8];
      f32x4 t1 = *(const f32x4*)&scratch[l * 52 + g * 8 + 4];
#pragma unroll
      for (int r = 0; r < 4; ++r) { acc[0][g][r] += t0[r]; acc[1][g][r] += t1[r]; }
    }
  }
  if (wid == 2) {
#pragma unroll
    for (int g = 0; g < 4; ++g) {
      f32x4 t0 = *(const f32x4*)&scratch[3328 + l * 52 + g * 12];
      f32x4 t1 = *(const f32x4*)&scratch[3328 + l * 52 + g * 12 + 4];
      f32x4 t2 = *(const f32x4*)&scratch[3328 + l * 52 + g * 12 + 8];
#pragma unroll
      for (int r = 0; r < 4; ++r) {
        acc[0][g][r] += t0[r]; acc[1][g][r] += t1[r]; acc[2][g][r] += t2[r];
      }
    }
  }
  __syncthreads();

  if (use_csr) {
    // assemble msg rows [64][80] in scratch, then coalesced copy-out
    if (wid == 0) {
#pragma unroll
      for (int g = 0; g < 4; ++g)
#pragma unroll
        for (int r = 0; r < 4; ++r) {
          int row = g * 16 + g16 + r;
          scratch[row * 80 + lr] = acc[0][g][r];
          scratch[row * 80 + 16 + lr] = acc[1][g][r];
        }
    }
    if (wid == 2) {
#pragma unroll
      for (int g = 0; g < 4; ++g)
#pragma unroll
        for (int r = 0; r < 4; ++r) {
          int row = g * 16 + g16 + r;
          scratch[row * 80 + 32 + lr * 3 + 0] = acc[0][g][r];
          scratch[row * 80 + 32 + lr * 3 + 1] = acc[1][g][r];
          scratch[row * 80 + 32 + lr * 3 + 2] = acc[2][g][r];
        }
    }
    __syncthreads();
    float* mp = msg + (long)e0 * 80;
#pragma unroll
    for (int q = 0; q < 5; ++q)
      *(f32x4*)&mp[tid * 20 + q * 4] = *(const f32x4*)&scratch[tid * 20 + q * 4];
  } else {
    if (wid == 0) {
#pragma unroll
      for (int g = 0; g < 4; ++g) {
        i32x4 dd = *(const i32x4*)&dsts[g * 16 + g16];
#pragma unroll
        for (int r = 0; r < 4; ++r) {
          float* base = agg + (long)dd[r] * 80;
          atomicAdd(base + lr, acc[0][g][r]);
          atomicAdd(base + 16 + lr, acc[1][g][r]);
        }
      }
    }
    if (wid == 2) {
#pragma unroll
      for (int g = 0; g < 4; ++g) {
        i32x4 dd = *(const i32x4*)&dsts[g * 16 + g16];
#pragma unroll
        for (int r = 0; r < 4; ++r) {
          float* base = agg + (long)dd[r] * 80;
          atomicAdd(base + 32 + lr * 3 + 0, acc[0][g][r]);
          atomicAdd(base + 32 + lr * 3 + 1, acc[1][g][r]);
          atomicAdd(base + 32 + lr * 3 + 2, acc[2][g][r]);
        }
      }
    }
  }
#undef FOLD_M0
#undef FOLD_M1
}

// ---- fused gather + self-interaction + stats (wave per node) ----
__global__ __launch_bounds__(256) void node_fused(
    const float* __restrict__ h, const float* __restrict__ A0,
    const float* __restrict__ A1p, const float* __restrict__ agg,
    const float* __restrict__ msg, const int* __restrict__ csr,
    const int* __restrict__ offs, const int* __restrict__ deg,
    float* __restrict__ outpre, float* __restrict__ stats, int use_csr) {
  __shared__ float A0s[1024], A1ps[256], red[96];
  const int tid = threadIdx.x;
  for (int i = tid; i < 1280; i += 256) {
    if (i < 1024) A0s[i] = A0[i];
    else A1ps[i - 1024] = A1p[i - 1024];
  }
  if (tid < 96) red[tid] = 0.f;
  __syncthreads();
  const int wid = tid >> 6, l = tid & 63;
  const int n = blockIdx.x * 4 + wid;
  if (n < NN) {
    const int dg = deg[n];
    const float inv = 1.f / fmaxf((float)dg, 1.f);
    float a0 = 0.f, a1 = 0.f;
    if (use_csr) {
      const int s = offs[n];
      int i = 0;
      for (; i + 2 <= dg; i += 2) {
        const float* rA = msg + (long)csr[s + i] * 80;
        const float* rB = msg + (long)csr[s + i + 1] * 80;
        a0 += rA[l] + rB[l];
        if (l < 16) a1 += rA[64 + l] + rB[64 + l];
      }
      if (i < dg) {
        const float* rA = msg + (long)csr[s + i] * 80;
        a0 += rA[l];
        if (l < 16) a1 += rA[64 + l];
      }
    } else {
      a0 = agg[(long)n * 80 + l];
      if (l < 16) a1 = agg[(long)n * 80 + 64 + l];
    }
    const float* hr = h + (long)n * 80;
    float valA;
    if (l < 32) {
      float x = 0.f;
#pragma unroll 8
      for (int u = 0; u < 32; ++u) x += hr[u] * A0s[u * 32 + l];
      valA = x * INV_SQRT_M0 + a0 * inv;
    } else {
      int j = l - 32, w = j / 3, i3 = j - w * 3;
      float x = 0.f;
#pragma unroll 8
      for (int u = 0; u < 16; ++u) x += hr[32 + u * 3 + i3] * A1ps[u * 16 + w];
      valA = x * INV_SQRT_M1 + a0 * inv;
    }
    float valB = 0.f;
    if (l < 16) {
      int j = 32 + l, w = j / 3, i3 = j - w * 3;
      float x = 0.f;
#pragma unroll 8
      for (int u = 0; u < 16; ++u) x += hr[32 + u * 3 + i3] * A1ps[u * 16 + w];
      valB = x * INV_SQRT_M1 + a1 * inv;
    }
    outpre[(long)n * 80 + l] = valA;
    if (l < 16) outpre[(long)n * 80 + 64 + l] = valB;
    if (l < 32) {
      atomicAdd(&red[l], valA);
      atomicAdd(&red[32 + l], valA * valA);
    } else {
      int w = (l - 32) / 3;
      atomicAdd(&red[64 + w], valA * valA);
    }
    if (l < 16) {
      int w = (32 + l) / 3;
      atomicAdd(&red[64 + w], valB * valB);
    }
  }
  __syncthreads();
  if (tid < 80) atomicAdd(&stats[tid], red[tid]);
}

__global__ void node_b(const float* __restrict__ outpre, const float* __restrict__ stats,
                       const float* __restrict__ bnw0, const float* __restrict__ bnb0,
                       const float* __restrict__ bnw1, const float* __restrict__ h,
                       float* __restrict__ out) {
  int idx = blockIdx.x * 256 + threadIdx.x;
  if (idx >= NN * 80) return;
  int c = idx % 80;
  float v = outpre[idx];
  const float invN = 1.f / NN;
  float o;
  if (c < 32) {
    float mu = stats[c] * invN;
    float var = stats[32 + c] * invN - mu * mu;
    o = (v - mu) * rsqrtf(var + EPSV) * bnw0[c] + bnb0[c];
  } else {
    int u = (c - 32) / 3;
    float nr = stats[64 + u] * invN;
    o = v * rsqrtf(nr + EPSV) * bnw1[u];
  }
  out[idx] = o + h[idx];
}

extern "C" void kernel_launch(void* const* d_in, const int* in_sizes, int n_in,
                              void* d_out, int out_size, void* d_ws, size_t ws_size,
                              hipStream_t stream) {
  const float* h    = (const float*)d_in[0];
  const int*   eidx = (const int*)d_in[1];
  const float* esh  = (const float*)d_in[2];
  const float* ef   = (const float*)d_in[3];
  const float* W1   = (const float*)d_in[4];
  const float* b1   = (const float*)d_in[5];
  const float* W2   = (const float*)d_in[6];
  const float* b2   = (const float*)d_in[7];
  const float* W3   = (const float*)d_in[8];
  const float* b3   = (const float*)d_in[9];
  const float* A0   = (const float*)d_in[10];
  const float* A1p  = (const float*)d_in[11];
  const float* bnw0 = (const float*)d_in[12];
  const float* bnb0 = (const float*)d_in[13];
  const float* bnw1 = (const float*)d_in[14];
  float* out = (float*)d_out;

  float* ws = (float*)d_ws;
  float* agg    = ws;                       // 800000
  float* stats  = ws + 800000;              // 80
  float* outpre = ws + 800080;              // 800000
  short* W3P    = (short*)(ws + 1600080);   // 147456 shorts
  short* W1P    = W3P + WNUM * 64;          // 4096
  short* W2P    = W1P + 4096;               // 4096  -> 77824 floats total
  int*   deg    = (int*)(ws + 1677904);     // 10000
  int*   slot   = deg + 10000;              // 10000
  int*   offs   = slot + 10000;             // 10001
  int*   csr    = offs + 10001;             // 160000 (+pad)
  float* msg    = ws + 1677904 + 190004;    // 12800000

  const size_t need = (size_t)(1677904 + 190004 + 12800000) * 4;
  const int use_csr = (ws_size >= need) ? 1 : 0;

  hipMemsetAsync(agg, 0, (size_t)800080 * sizeof(float), stream);
  hipMemsetAsync(deg, 0, (size_t)20000 * sizeof(int), stream);

  prep_weights<<<(WNUM * 64 + 8192 + 255) / 256, 256, 0, stream>>>(W1, W2, W3, W1P,
                                                                   W2P, W3P);
  edge_count<<<(NE + 255) / 256, 256, 0, stream>>>(eidx, deg);
  if (use_csr) {
    scan_deg<<<1, 256, 0, stream>>>(deg, offs);
    edge_place<<<(NE + 255) / 256, 256, 0, stream>>>(eidx, offs, slot, csr);
  }
  edge_kernel<<<NE / 64, 256, 0, stream>>>(h, eidx, esh, ef, W1P, b1, W2P, b2, W3P, b3,
                                           agg, msg, use_csr);
  node_fused<<<(NN + 3) / 4, 256, 0, stream>>>(h, A0, A1p, agg, msg, csr, offs, deg,
                                               outpre, stats, use_csr);
  node_b<<<(NN * 80 + 255) / 256, 256, 0, stream>>>(outpre, stats, bnw0, bnb0, bnw1, h,
                                                    out);
}